// Round 7
// baseline (143.429 us; speedup 1.0000x reference)
//
#include <hip/hip_runtime.h>
#include <stdint.h>

// Loss = mean(0.5*(o-t)^2 * ef(t)) over N = 64*1*512*512 = 2^24 fp32 elements.
// ef(t) = BETA - exp((A-1)*ln(x) - x + BIAS),  x = (t - LOC)/SCALE
// Measured path model: VGPR-bound reads cap at ~3.0 (coherent) / 3.7 (NT) /
// ~4.3 (mixed) TB/s regardless of policy mix (R11 rebalance: null), MLP, or
// occupancy. Poison fills write at 6.6 TB/s => HBM/fabric is NOT the cap;
// the vector-load RETURN path is the suspect. tgt/out IF$ residency follows
// allocation policy (cached allocates; nt/sc1 don't — R9). Monolithic asm
// regressions (R8/R9) came from defeating compiler scheduling; builtins are
// the right mechanism.
// R13: test the one read mechanism with a DIFFERENT return path:
// global_load_lds (DMA direct to LDS, no VGPR writeback). out staged via
// 8x global_load_lds width=16 CACHED (out becomes IF$-resident); tgt via NT
// vector loads (known 3.7 path). __syncthreads drains vmcnt, then
// ds_read_b128 + compute. Predict: independent DMA return path -> main
// ~20-25us (wall ~115-120); shared memory-side cap -> ~30-33 (wall ~125-128);
// DMA serializes -> wall >= 131, revert to exact-R7 next.
// R14 = R13 resubmitted verbatim (GPU acquisition timeout, never measured).

#define NBLOCKS 2048
#define NTHREADS 256
#define F4_PER_THREAD 8   // 2048*256*8*4 = 2^24 elements exactly

typedef float vf4 __attribute__((ext_vector_type(4)));

__device__ __forceinline__ float ef_term(float o, float y) {
    constexpr float A_M1      = -0.93555708575356741f;  // EST_A - 1
    constexpr float NEG_LOC   =  1.1328205299926424e-27f;
    constexpr float INV_SCALE =  0.65034886603218541f;  // 1/1.5376362609160314
    constexpr float BIAS      = -56.8416699f;
    constexpr float BETA      =  5.0f;

    float x  = (y + NEG_LOC) * INV_SCALE;           // > 0 for y >= 0
    float ex = __expf(fmaf(A_M1, __logf(x), BIAS - x));
    float ef = BETA - ex;                            // == c when y == 0
    float d  = o - y;
    return 0.5f * d * d * ef;
}

__device__ __forceinline__ vf4 ld_nt(const vf4* p) {
    return __builtin_nontemporal_load(p);
}

// Async DMA: 16 bytes per lane, global -> LDS. LDS dest is wave-uniform
// base + lane*16 (hardware rule); global src is per-lane. Cached policy
// (aux=0) so the source line allocates into L2/IF$.
__device__ __forceinline__ void dma16(const void* g, void* l) {
    __builtin_amdgcn_global_load_lds(
        (const __attribute__((address_space(1))) void*)g,
        (__attribute__((address_space(3))) void*)l,
        16, 0, 0);
}

__device__ __forceinline__ float block_reduce(float acc) {
    #pragma unroll
    for (int off = 32; off > 0; off >>= 1)
        acc += __shfl_down(acc, off, 64);
    __shared__ float wsum[NTHREADS / 64];
    int lane = threadIdx.x & 63;
    int wave = threadIdx.x >> 6;
    if (lane == 0) wsum[wave] = acc;
    __syncthreads();
    float s = 0.f;
    if (threadIdx.x == 0) {
        #pragma unroll
        for (int w = 0; w < NTHREADS / 64; ++w) s += wsum[w];
    }
    return s;  // valid on thread 0 only
}

// Fast path: n == NBLOCKS*NTHREADS*F4_PER_THREAD*4 exactly.
// Round r fully coalesced: float4 index = chunk_base + r*NTHREADS + tid.
// out: DMA to LDS (cached, IF$-allocating). tgt: NT vector loads.
__global__ __launch_bounds__(NTHREADS, 2) void ef_loss_partial_fast(
    const float* __restrict__ out, const float* __restrict__ tgt,
    float* __restrict__ partials) {
    __shared__ vf4 lds4[NTHREADS * F4_PER_THREAD];   // 32 KB
    const int tid  = threadIdx.x;
    const int wave = tid >> 6;
    const int base = blockIdx.x * (NTHREADS * F4_PER_THREAD) + tid;
    const vf4* __restrict__ op = (const vf4*)out;
    const vf4* __restrict__ tp = (const vf4*)tgt;

    // Issue 8 LDS-DMA reads for out. Slot for thread tid, round r is
    // r*NTHREADS + tid; per wave that is uniform base r*NTHREADS + wave*64
    // plus lane*16B — exactly the HW's linear dest rule.
    #pragma unroll
    for (int r = 0; r < F4_PER_THREAD; ++r)
        dma16((const void*)(op + base + r * NTHREADS),
              (void*)&lds4[r * NTHREADS + wave * 64]);

    // tgt via NT vector loads (VGPR return path).
    vf4 t0  = ld_nt(tp + base + 0 * NTHREADS);
    vf4 t1  = ld_nt(tp + base + 1 * NTHREADS);
    vf4 t2  = ld_nt(tp + base + 2 * NTHREADS);
    vf4 t3  = ld_nt(tp + base + 3 * NTHREADS);
    vf4 t4v = ld_nt(tp + base + 4 * NTHREADS);
    vf4 t5  = ld_nt(tp + base + 5 * NTHREADS);
    vf4 t6  = ld_nt(tp + base + 6 * NTHREADS);
    vf4 t7  = ld_nt(tp + base + 7 * NTHREADS);

    __syncthreads();   // drains vmcnt (DMA + NT loads) before LDS reads

    float a0 = 0.f, a1 = 0.f, a2 = 0.f, a3 = 0.f;

#define EF_ROUND(r, tv)                                                     \
    do {                                                                    \
        vf4 o = lds4[(r) * NTHREADS + tid];                                 \
        a0 += ef_term(o.x, tv.x);                                           \
        a1 += ef_term(o.y, tv.y);                                           \
        a2 += ef_term(o.z, tv.z);                                           \
        a3 += ef_term(o.w, tv.w);                                           \
    } while (0)

    EF_ROUND(0, t0);
    EF_ROUND(1, t1);
    EF_ROUND(2, t2);
    EF_ROUND(3, t3);
    EF_ROUND(4, t4v);
    EF_ROUND(5, t5);
    EF_ROUND(6, t6);
    EF_ROUND(7, t7);
#undef EF_ROUND

    float s = block_reduce((a0 + a1) + (a2 + a3));
    if (threadIdx.x == 0) partials[blockIdx.x] = s;
}

// Generic fallback (any n).
__global__ __launch_bounds__(NTHREADS) void ef_loss_partial_gen(
    const float* __restrict__ out, const float* __restrict__ tgt,
    float* __restrict__ partials, int n) {
    const int idx    = blockIdx.x * blockDim.x + threadIdx.x;
    const int stride = gridDim.x * blockDim.x;
    const int n4     = n >> 2;
    const float4* __restrict__ o4 = (const float4*)out;
    const float4* __restrict__ t4 = (const float4*)tgt;

    float acc = 0.f;
    for (int i = idx; i < n4; i += stride) {
        float4 o = o4[i];
        float4 t = t4[i];
        acc += ef_term(o.x, t.x);
        acc += ef_term(o.y, t.y);
        acc += ef_term(o.z, t.z);
        acc += ef_term(o.w, t.w);
    }
    for (int i = (n4 << 2) + idx; i < n; i += stride)
        acc += ef_term(out[i], tgt[i]);

    float s = block_reduce(acc);
    if (threadIdx.x == 0) partials[blockIdx.x] = s;
}

__global__ __launch_bounds__(NTHREADS) void ef_loss_finalize(
    const float* __restrict__ partials, float* __restrict__ result,
    int nblocks, float inv_n) {
    float acc = 0.f;
    for (int i = threadIdx.x; i < nblocks; i += blockDim.x)
        acc += partials[i];
    float s = block_reduce(acc);
    if (threadIdx.x == 0) result[0] = s * inv_n;
}

extern "C" void kernel_launch(void* const* d_in, const int* in_sizes, int n_in,
                              void* d_out, int out_size, void* d_ws, size_t ws_size,
                              hipStream_t stream) {
    const float* out_p = (const float*)d_in[0];   // "output"
    const float* tgt_p = (const float*)d_in[1];   // "target"
    float* partials = (float*)d_ws;               // NBLOCKS floats = 8 KB
    float* result   = (float*)d_out;
    const int n = in_sizes[0];

    if (n == NBLOCKS * NTHREADS * F4_PER_THREAD * 4) {
        ef_loss_partial_fast<<<NBLOCKS, NTHREADS, 0, stream>>>(out_p, tgt_p, partials);
    } else {
        ef_loss_partial_gen<<<NBLOCKS, NTHREADS, 0, stream>>>(out_p, tgt_p, partials, n);
    }
    ef_loss_finalize<<<1, NTHREADS, 0, stream>>>(partials, result, NBLOCKS,
                                                 1.0f / (float)n);
}